// Round 1
// baseline (77.830 us; speedup 1.0000x reference)
//
#include <hip/hip_runtime.h>
#include <hip/hip_bf16.h>
#include <math.h>

#define NN 1024
#define MM 1024
#define DD 256
#define TILE 64
#define PITCH 260   // 256 + 4 floats pad -> breaks LDS bank aliasing, keeps 16B align

// ---------------- wave/block reduce helpers ----------------
__device__ inline float wredMax(float v) {
#pragma unroll
  for (int o = 32; o > 0; o >>= 1) v = fmaxf(v, __shfl_down(v, o, 64));
  return v;
}
__device__ inline float wredSum(float v) {
#pragma unroll
  for (int o = 32; o > 0; o >>= 1) v += __shfl_down(v, o, 64);
  return v;
}

// ---------------- distance matrix: s[i][j] = -sum_d |x[i,d]-y[j,d]| ----------------
__global__ __launch_bounds__(256) void k_dist(const float* __restrict__ zx,
                                              const float* __restrict__ zy,
                                              float* __restrict__ S) {
  __shared__ float xs[TILE * PITCH];
  __shared__ float ys[TILE * PITCH];
  const int i0 = blockIdx.y * TILE;
  const int j0 = blockIdx.x * TILE;
  const int t = threadIdx.x;

  // stage 64 rows x 256 floats for both x and y (float4, fully coalesced)
#pragma unroll
  for (int k = 0; k < 16; ++k) {
    int idx4 = t + k * 256;          // float4 index within 64x256 tile
    int r = idx4 >> 6;               // 64 float4 per row
    int c4 = idx4 & 63;
    float4 vx = reinterpret_cast<const float4*>(zx + (size_t)(i0 + r) * DD)[c4];
    float4 vy = reinterpret_cast<const float4*>(zy + (size_t)(j0 + r) * DD)[c4];
    *reinterpret_cast<float4*>(&xs[r * PITCH + c4 * 4]) = vx;
    *reinterpret_cast<float4*>(&ys[r * PITCH + c4 * 4]) = vy;
  }
  __syncthreads();

  const int tx = t & 15;
  const int ty = t >> 4;
  float acc[4][4];
#pragma unroll
  for (int a = 0; a < 4; ++a)
#pragma unroll
    for (int b = 0; b < 4; ++b) acc[a][b] = 0.f;

  for (int d4 = 0; d4 < DD / 4; ++d4) {
    float4 xa[4], yb[4];
#pragma unroll
    for (int a = 0; a < 4; ++a)
      xa[a] = *reinterpret_cast<const float4*>(&xs[(ty + a * 16) * PITCH + d4 * 4]);
#pragma unroll
    for (int b = 0; b < 4; ++b)
      yb[b] = *reinterpret_cast<const float4*>(&ys[(tx + b * 16) * PITCH + d4 * 4]);
#pragma unroll
    for (int a = 0; a < 4; ++a)
#pragma unroll
      for (int b = 0; b < 4; ++b) {
        acc[a][b] += fabsf(xa[a].x - yb[b].x) + fabsf(xa[a].y - yb[b].y) +
                     fabsf(xa[a].z - yb[b].z) + fabsf(xa[a].w - yb[b].w);
      }
  }

#pragma unroll
  for (int a = 0; a < 4; ++a) {
    int i = i0 + ty + a * 16;
#pragma unroll
    for (int b = 0; b < 4; ++b) {
      int j = j0 + tx + b * 16;
      S[(size_t)i * MM + j] = -acc[a][b];
    }
  }
}

// ---------------- row softmax stats ----------------
__global__ __launch_bounds__(256) void k_rowstats(const float* __restrict__ S,
                                                  float* __restrict__ rowMax,
                                                  float* __restrict__ rowSum) {
  const int i = blockIdx.x;
  const int t = threadIdx.x;
  float4 v = reinterpret_cast<const float4*>(S + (size_t)i * MM)[t];
  float m = fmaxf(fmaxf(v.x, v.y), fmaxf(v.z, v.w));
  __shared__ float red[4];
  m = wredMax(m);
  const int lane = t & 63, wv = t >> 6;
  if (lane == 0) red[wv] = m;
  __syncthreads();
  m = fmaxf(fmaxf(red[0], red[1]), fmaxf(red[2], red[3]));
  __syncthreads();
  float s = __expf(v.x - m) + __expf(v.y - m) + __expf(v.z - m) + __expf(v.w - m);
  s = wredSum(s);
  if (lane == 0) red[wv] = s;
  __syncthreads();
  if (t == 0) {
    rowMax[i] = m;
    rowSum[i] = red[0] + red[1] + red[2] + red[3];
  }
}

// ---------------- column softmax stats (partials over row stripes) ----------------
__global__ __launch_bounds__(256) void k_colpart(const float* __restrict__ S,
                                                 float* __restrict__ colMpart,
                                                 float* __restrict__ colSpart) {
  // grid (64, 4): block covers cols [bx*16, +16), rows [by*256, +256)
  const int tx = threadIdx.x & 15;
  const int ty = threadIdx.x >> 4;         // 0..15
  const int j = blockIdx.x * 16 + tx;
  const int i0 = blockIdx.y * 256;
  float m = -1e30f, s = 0.f;
  for (int k = 0; k < 16; ++k) {
    int i = i0 + ty + k * 16;
    float v = S[(size_t)i * MM + j];
    if (v > m) {
      s = s * __expf(m - v) + 1.f;
      m = v;
    } else {
      s += __expf(v - m);
    }
  }
  __shared__ float mS[16][16];
  __shared__ float sS[16][16];
  mS[ty][tx] = m;
  sS[ty][tx] = s;
  __syncthreads();
  if (ty == 0) {
    float mm = mS[0][tx], ss = sS[0][tx];
#pragma unroll
    for (int k = 1; k < 16; ++k) {
      float m2 = mS[k][tx], s2 = sS[k][tx];
      float mn = fmaxf(mm, m2);
      ss = ss * __expf(mm - mn) + s2 * __expf(m2 - mn);
      mm = mn;
    }
    colMpart[(size_t)blockIdx.y * MM + j] = mm;
    colSpart[(size_t)blockIdx.y * MM + j] = ss;
  }
}

__global__ __launch_bounds__(256) void k_colmerge(const float* __restrict__ colMpart,
                                                  const float* __restrict__ colSpart,
                                                  float* __restrict__ colMax,
                                                  float* __restrict__ colSum) {
  const int j = blockIdx.x * 256 + threadIdx.x;  // grid 4 blocks
  float m = colMpart[j], s = colSpart[j];
#pragma unroll
  for (int k = 1; k < 4; ++k) {
    float m2 = colMpart[(size_t)k * MM + j], s2 = colSpart[(size_t)k * MM + j];
    float mn = fmaxf(m, m2);
    s = s * __expf(m - mn) + s2 * __expf(m2 - mn);
    m = mn;
  }
  colMax[j] = m;
  colSum[j] = s;
}

// ---------------- zero accumulators ----------------
__global__ void k_zero(float* acc) {
  if (threadIdx.x < 2) acc[threadIdx.x] = 0.f;
}

// ---------------- weighted accumulation ----------------
__global__ __launch_bounds__(256) void k_accum(const float* __restrict__ S,
                                               const float* __restrict__ rowMax,
                                               const float* __restrict__ rowSum,
                                               const float* __restrict__ colMax,
                                               const float* __restrict__ colSum,
                                               float* __restrict__ acc) {
  const int i = blockIdx.x;
  const int t = threadIdx.x;
  float4 v = reinterpret_cast<const float4*>(S + (size_t)i * MM)[t];
  const float rm = rowMax[i];
  const float rinv = 1.f / rowSum[i];
  float4 cm = reinterpret_cast<const float4*>(colMax)[t];
  float4 cs = reinterpret_cast<const float4*>(colSum)[t];
  float num = 0.f, den = 0.f;
#define DO_COMP(VX, CMX, CSX)                      \
  {                                                \
    float a = __expf((VX) - rm) * rinv;            \
    float b = __expf((VX) - (CMX)) / (CSX);        \
    float w = a + b - a * b;                       \
    num += w * (VX);                               \
    den += w;                                      \
  }
  DO_COMP(v.x, cm.x, cs.x)
  DO_COMP(v.y, cm.y, cs.y)
  DO_COMP(v.z, cm.z, cs.z)
  DO_COMP(v.w, cm.w, cs.w)
#undef DO_COMP
  num = wredSum(num);
  den = wredSum(den);
  __shared__ float rn[4], rd[4];
  const int lane = t & 63, wv = t >> 6;
  if (lane == 0) { rn[wv] = num; rd[wv] = den; }
  __syncthreads();
  if (t == 0) {
    atomicAdd(&acc[0], rn[0] + rn[1] + rn[2] + rn[3]);
    atomicAdd(&acc[1], rd[0] + rd[1] + rd[2] + rd[3]);
  }
}

__global__ void k_final(const float* __restrict__ acc, float* __restrict__ out) {
  out[0] = acc[0] / acc[1];
}

// ---------------- launch ----------------
extern "C" void kernel_launch(void* const* d_in, const int* in_sizes, int n_in,
                              void* d_out, int out_size, void* d_ws, size_t ws_size,
                              hipStream_t stream) {
  const float* zx = (const float*)d_in[0];
  const float* zy = (const float*)d_in[1];
  float* out = (float*)d_out;

  float* ws = (float*)d_ws;
  float* S = ws;                          // N*M
  float* rowMax = S + (size_t)NN * MM;    // N
  float* rowSum = rowMax + NN;            // N
  float* colMax = rowSum + NN;            // M
  float* colSum = colMax + MM;            // M
  float* colMpart = colSum + MM;          // 4*M
  float* colSpart = colMpart + 4 * MM;    // 4*M
  float* acc = colSpart + 4 * MM;         // 2

  k_zero<<<1, 64, 0, stream>>>(acc);
  k_dist<<<dim3(MM / TILE, NN / TILE), 256, 0, stream>>>(zx, zy, S);
  k_rowstats<<<NN, 256, 0, stream>>>(S, rowMax, rowSum);
  k_colpart<<<dim3(MM / 16, 4), 256, 0, stream>>>(S, colMpart, colSpart);
  k_colmerge<<<4, 256, 0, stream>>>(colMpart, colSpart, colMax, colSum);
  k_accum<<<NN, 256, 0, stream>>>(S, rowMax, rowSum, colMax, colSum, acc);
  k_final<<<1, 1, 0, stream>>>(acc, out);
}